// Round 1
// baseline (105.731 us; speedup 1.0000x reference)
//
#include <hip/hip_runtime.h>

constexpr int BLK = 256;

struct F3 { float x, y, z; };
struct F4 { float x, y, z, w; };

__device__ inline F3 cross3(const F3 a, const F3 b) {
    return { a.y * b.z - a.z * b.y,
             a.z * b.x - a.x * b.z,
             a.x * b.y - a.y * b.x };
}

// v + w*t + cross(qv, t), t = 2*cross(qv, v)   (matches _qrot)
__device__ inline F3 qrot(const F4 q, const F3 v) {
    F3 qv{ q.x, q.y, q.z };
    F3 t = cross3(qv, v);
    t.x *= 2.f; t.y *= 2.f; t.z *= 2.f;
    F3 c = cross3(qv, t);
    return { v.x + q.w * t.x + c.x,
             v.y + q.w * t.y + c.y,
             v.z + q.w * t.z + c.z };
}

// (x,y,z,w) layout, matches _qmul
__device__ inline F4 qmul(const F4 a, const F4 b) {
    return { a.w * b.x + a.x * b.w + a.y * b.z - a.z * b.y,
             a.w * b.y - a.x * b.z + a.y * b.w + a.z * b.x,
             a.w * b.z + a.x * b.y - a.y * b.x + a.z * b.w,
             a.w * b.w - a.x * b.x - a.y * b.y - a.z * b.z };
}

__global__ __launch_bounds__(BLK) void pose_graph_err_kernel(
    const float* __restrict__ nodes,   // [N_NODES, 7]
    const float* __restrict__ poses,   // [N_EDGES, 7]
    const int*   __restrict__ edges,   // [N_EDGES, 2] (int32)
    float*       __restrict__ out,     // [N_EDGES, 6]
    int n_edges)
{
    __shared__ float s_pose[BLK * 7];  // 7168 B
    __shared__ float s_out [BLK * 6];  // 6144 B

    const int tid = threadIdx.x;
    const int block_start = blockIdx.x * BLK;
    const int cnt = min(BLK, n_edges - block_start);

    // ---- stage poses (vectorized when the block is full) ----
    if (cnt == BLK) {
        const float4* pv = (const float4*)(poses + (size_t)block_start * 7);
        float4* sp = (float4*)s_pose;
        #pragma unroll
        for (int i = tid; i < BLK * 7 / 4; i += BLK) sp[i] = pv[i];
    } else {
        for (int i = tid; i < cnt * 7; i += BLK)
            s_pose[i] = poses[(size_t)block_start * 7 + i];
    }
    __syncthreads();

    F3 rho{0.f,0.f,0.f}, phi{0.f,0.f,0.f};
    const int e = block_start + tid;
    if (tid < cnt) {
        // pose for this edge
        const float* sp = s_pose + tid * 7;
        F3 tp{ sp[0], sp[1], sp[2] };
        F4 qp{ sp[3], sp[4], sp[5], sp[6] };

        // edge indices (coalesced 8B/lane)
        const int2 ij = ((const int2*)edges)[e];
        const float* n1 = nodes + (size_t)ij.x * 7;
        const float* n2 = nodes + (size_t)ij.y * 7;

        F3 t1{ n1[0], n1[1], n1[2] };
        F4 q1{ n1[3], n1[4], n1[5], n1[6] };
        F3 t2{ n2[0], n2[1], n2[2] };
        F4 q2{ n2[3], n2[4], n2[5], n2[6] };

        // inv(node1)
        F4 qi{ -q1.x, -q1.y, -q1.z, q1.w };
        F3 ti = qrot(qi, t1);
        ti.x = -ti.x; ti.y = -ti.y; ti.z = -ti.z;

        // A = pose * inv(node1)
        F3 ra = qrot(qp, ti);
        F3 tA{ tp.x + ra.x, tp.y + ra.y, tp.z + ra.z };
        F4 qA = qmul(qp, qi);

        // E = A * node2
        F3 rb = qrot(qA, t2);
        F3 tE{ tA.x + rb.x, tA.y + rb.y, tA.z + rb.z };
        F4 qE = qmul(qA, q2);

        // ---- se3_log ----
        if (qE.w < 0.f) { qE.x = -qE.x; qE.y = -qE.y; qE.z = -qE.z; qE.w = -qE.w; }
        const float n2q = qE.x * qE.x + qE.y * qE.y + qE.z * qE.z;
        const float nq = sqrtf(n2q);
        const float theta = 2.f * atan2f(nq, qE.w);
        const bool small = nq < 1e-6f;
        const float scale = small ? (2.f / fmaxf(qE.w, 1e-12f)) : (theta / nq);
        phi = { scale * qE.x, scale * qE.y, scale * qE.z };

        const float th2 = theta * theta;
        const bool tiny = theta < 1e-4f;
        float coef;
        if (tiny) {
            coef = 1.f / 12.f + th2 / 720.f;
        } else {
            coef = 1.f / th2 - (1.f + cosf(theta)) / (2.f * theta * sinf(theta));
        }

        const F3 pxt  = cross3(phi, tE);
        const F3 ppxt = cross3(phi, pxt);
        rho = { tE.x - 0.5f * pxt.x + coef * ppxt.x,
                tE.y - 0.5f * pxt.y + coef * ppxt.y,
                tE.z - 0.5f * pxt.z + coef * ppxt.z };

        float* so = s_out + tid * 6;
        so[0] = rho.x; so[1] = rho.y; so[2] = rho.z;
        so[3] = phi.x; so[4] = phi.y; so[5] = phi.z;
    }
    __syncthreads();

    // ---- coalesced float4 store of the block's output ----
    if (cnt == BLK) {
        float4* ov = (float4*)(out + (size_t)block_start * 6);
        const float4* sv = (const float4*)s_out;
        #pragma unroll
        for (int i = tid; i < BLK * 6 / 4; i += BLK) ov[i] = sv[i];
    } else {
        for (int i = tid; i < cnt * 6; i += BLK)
            out[(size_t)block_start * 6 + i] = s_out[i];
    }
}

extern "C" void kernel_launch(void* const* d_in, const int* in_sizes, int n_in,
                              void* d_out, int out_size, void* d_ws, size_t ws_size,
                              hipStream_t stream) {
    const float* nodes = (const float*)d_in[0];
    const float* poses = (const float*)d_in[1];
    const int*   edges = (const int*)d_in[2];
    float* out = (float*)d_out;

    const int n_edges = in_sizes[2] / 2;
    const int nblocks = (n_edges + BLK - 1) / BLK;
    pose_graph_err_kernel<<<nblocks, BLK, 0, stream>>>(nodes, poses, edges, out, n_edges);
}